// Round 2
// baseline (242.103 us; speedup 1.0000x reference)
//
#include <hip/hip_runtime.h>
#include <stdint.h>

// Exact fp32 reproduction of the numpy reference requires no FMA contraction
// and identical association order everywhere below.
#pragma clang fp contract(off)

#define B_    4
#define NV_   6890
#define NF_   27552     // 2*13776
#define IMG_  128
#define UV_   256
#define NPIX  (IMG_*IMG_)

#define TS_     8                 // tile edge in pixels
#define TPB_    (IMG_/TS_)        // 16 tiles per row/col
#define NTILE_  (TPB_*TPB_)       // 256 tiles per batch
#define NBIN_   (B_*NTILE_)       // 1024 bins
#define LIST_CAP (2*1024*1024)    // entries (8 MB); measured need ~1.2M
#define MAXC_   (LIST_CAP/256 + NBIN_)  // 9216: hard bound on work chunks

// ---------------------------------------------------------------- projection
__global__ void __launch_bounds__(256) project_k(
    const float* __restrict__ cam, const float* __restrict__ verts,
    float* __restrict__ vp) {
  int idx = blockIdx.x * 256 + threadIdx.x;
  if (idx >= B_ * NV_) return;
  int b = idx / NV_;
  float c0 = cam[b * 3 + 0], c1 = cam[b * 3 + 1], c2 = cam[b * 3 + 2];
  float tz = 500.0f / (64.0f * c0);                  // FLENGTH/(p*cam0), p=64
  const float* src = verts + (size_t)idx * 3;
  float* dst = vp + (size_t)idx * 3;
  dst[0] = c0 * (src[0] + c1);
  dst[1] = c0 * (src[1] + c2);
  dst[2] = src[2] + tz;
}

// ------------------------------------------------------------------- binning
// Backface cull (area_c < -1e-3, bit-safe bound proven in R1) + bbox(+-1px)
// -> range of overlapped 8x8 tiles. +-1 px margin: accepted pixels can exceed
// the fp bbox by <~1e-3 px only (fp error of w-tests ~1e-5 NDC).
__device__ __forceinline__ int face_tiles(
    const float* __restrict__ vp, const int* __restrict__ faces, int b, int f,
    int& tx0, int& tx1, int& ty0, int& ty1) {
  int ia = faces[f * 3 + 0], ib = faces[f * 3 + 1], ic = faces[f * 3 + 2];
  const float* vb = vp + (size_t)b * NV_ * 3;
  float x0 = vb[ia * 3 + 0], y0 = vb[ia * 3 + 1];
  float x1 = vb[ib * 3 + 0], y1 = vb[ib * 3 + 1];
  float x2 = vb[ic * 3 + 0], y2 = vb[ic * 3 + 1];
  float area_c = (x1 - x0) * (y2 - y0) - (y1 - y0) * (x2 - x0);
  if (area_c < -1e-3f) return 0;
  float xmn = fminf(x0, fminf(x1, x2)), xmx = fmaxf(x0, fmaxf(x1, x2));
  float ymn = fminf(y0, fminf(y1, y2)), ymx = fmaxf(y0, fmaxf(y1, y2));
  int jlo = (int)floorf((xmn + 1.0f) * 64.0f - 0.5f) - 1;
  int jhi = (int)ceilf ((xmx + 1.0f) * 64.0f - 0.5f) + 1;
  int ilo = (int)floorf((1.0f - ymx) * 64.0f - 0.5f) - 1;
  int ihi = (int)ceilf ((1.0f - ymn) * 64.0f - 0.5f) + 1;
  if (jhi < 0 || ihi < 0 || jlo > IMG_ - 1 || ilo > IMG_ - 1) return 0;
  jlo = max(jlo, 0); ilo = max(ilo, 0);
  jhi = min(jhi, IMG_ - 1); ihi = min(ihi, IMG_ - 1);
  tx0 = jlo >> 3; tx1 = jhi >> 3; ty0 = ilo >> 3; ty1 = ihi >> 3;
  return 1;
}

// Block-local LDS count aggregation (R5-validated). Also caches the packed
// tile rect per (b,f) so bin_fill_k skips recomputing face_tiles.
__global__ void __launch_bounds__(256) bin_count_k(
    const float* __restrict__ vp, const int* __restrict__ faces,
    int* __restrict__ cnt, int* __restrict__ rects) {
  __shared__ int scnt[NTILE_];
  int f = blockIdx.x * 256 + threadIdx.x;
  int b = blockIdx.y;
  scnt[threadIdx.x] = 0;
  __syncthreads();
  int tx0, tx1, ty0, ty1;
  int valid = (f < NF_) ? face_tiles(vp, faces, b, f, tx0, tx1, ty0, ty1) : 0;
  if (f < NF_)
    rects[(size_t)b * NF_ + f] =
        valid ? (tx0 | (tx1 << 4) | (ty0 << 8) | (ty1 << 12) | (1 << 16)) : 0;
  if (valid)
    for (int ty = ty0; ty <= ty1; ++ty)
      for (int tx = tx0; tx <= tx1; ++tx)
        atomicAdd(&scnt[ty * TPB_ + tx], 1);
  __syncthreads();
  int t = threadIdx.x;
  int v = scnt[t];
  if (v > 0) atomicAdd(&cnt[b * NTILE_ + t], v);
}

// Scan bin counts -> offsets; also scan chunk counts (ceil(cnt/256)) into a
// flat balanced work list of (bin, chunk) pairs; total chunk count -> nC.
__global__ void __launch_bounds__(1024) scan_k(
    const int* __restrict__ cnt, int* __restrict__ off, int* __restrict__ cur,
    int* __restrict__ work, int* __restrict__ nC) {
  __shared__ int sm[NBIN_];
  int t = threadIdx.x;
  int v = cnt[t];
  sm[t] = v;
  __syncthreads();
  for (int d = 1; d < NBIN_; d <<= 1) {
    int u = (t >= d) ? sm[t - d] : 0;
    __syncthreads();
    sm[t] += u;
    __syncthreads();
  }
  int o = sm[t] - v;
  off[t] = o;
  cur[t] = o;
  int nch = (v + 255) >> 8;
  __syncthreads();
  sm[t] = nch;
  __syncthreads();
  for (int d = 1; d < NBIN_; d <<= 1) {
    int u = (t >= d) ? sm[t - d] : 0;
    __syncthreads();
    sm[t] += u;
    __syncthreads();
  }
  int cb = sm[t] - nch;
  if (t == NBIN_ - 1) nC[0] = sm[t];
  for (int c = 0; c < nch; ++c) work[cb + c] = t | (c << 10);
}

// Block-local fill (R5-validated), using the cached rects from bin_count_k.
__global__ void __launch_bounds__(256) bin_fill_k(
    const int* __restrict__ rects, int* __restrict__ cur,
    int* __restrict__ list) {
  __shared__ int scnt[NTILE_];
  __shared__ int sbase[NTILE_];
  int f = blockIdx.x * 256 + threadIdx.x;
  int b = blockIdx.y;
  scnt[threadIdx.x] = 0;
  __syncthreads();
  int rv = (f < NF_) ? rects[(size_t)b * NF_ + f] : 0;
  int valid = rv >> 16;
  int tx0 = rv & 15, tx1 = (rv >> 4) & 15;
  int ty0 = (rv >> 8) & 15, ty1 = (rv >> 12) & 15;
  if (valid)
    for (int ty = ty0; ty <= ty1; ++ty)
      for (int tx = tx0; tx <= tx1; ++tx)
        atomicAdd(&scnt[ty * TPB_ + tx], 1);
  __syncthreads();
  int t = threadIdx.x;
  int v = scnt[t];
  if (v > 0) sbase[t] = atomicAdd(&cur[b * NTILE_ + t], v);
  __syncthreads();
  scnt[t] = 0;            // reuse as per-bin rank counter
  __syncthreads();
  if (valid)
    for (int ty = ty0; ty <= ty1; ++ty)
      for (int tx = tx0; tx <= tx1; ++tx) {
        int bin = ty * TPB_ + tx;
        int r = atomicAdd(&scnt[bin], 1);
        int slot = sbase[bin] + r;
        if (slot < LIST_CAP) list[slot] = f;
      }
}

// ---------------------------------------------------------------- rasterizer
// One 256-thread block per work chunk (bin, 256 faces). Inside test
// `area>0 && !(min3(w)<0)` == reference's post-divide b>=0 (R3-R5 validated,
// absmax 0.0; min3 preserves -0 semantics since !(-0<0)==true).
//
// R8 (this round): two-pass exact-deferral. The old per-iteration gate ran
// the ~85-instr exact 7-divide chain whenever ANY lane gate-passed -- with
// per-lane prefix-minima scattered across q, that was nearly every iteration
// (wave-level cost ~100 instr/iter, the measured VALU bound).
//  Pass 1 (branchless): approx zpa only (rel err <= ~1e-4: positive sums,
//    v_rcp 1ulp). Per-lane min zpa over certainly-window-valid candidates
//    (uint order == float order for positive floats).
//  Pass 2: per-lane static threshold thr = min(win, seed)*1.001 (margin
//    1e-3 >> 1e-4). Faces with zpa > thr and outside the window-uncertainty
//    bands provably cannot improve zkey: either zp > seed (exact z already
//    in zkey, strict), or zp > zp(win-face) which we submit exactly.
//    Ambiguous faces set a bit in a per-lane 64-bit qmask (~1.3 bits).
//  Chain tail: per-lane iteration over qmask bits -> the wave executes
//    max-popcount (~2-4) exact chains per segment instead of ~40.
// Scalar zmin skips: pass 1 vs wavemax(seed) (exact, no margin: zp >= zmin >
// seed); pass 2 vs wavemax(min(win,seed))*1.001 (margin required: win is
// approx). Seed = coherent atomicMin(zkey,~0ull) snapshot (hi word only,
// monotone decreasing -> pruning exact; NaN/empty clamped to +inf).
// R7's bitonic sort/scatter removed (1.25M bank conflicts, weak zmin bound
// on this geometry: face z-extent ~ scene z-spread).
__global__ void __launch_bounds__(256) raster_k(
    const float* __restrict__ vp, const int* __restrict__ faces,
    const int* __restrict__ list, const int* __restrict__ cnt,
    const int* __restrict__ off, const int* __restrict__ work,
    const int* __restrict__ nC, unsigned long long* __restrict__ zkey) {
  __shared__ float4 fd[4][5][64];   // [wave][field][lane]
  __shared__ unsigned long long mg[4][64];
  __shared__ float zmn[4][64];      // face zmin (exact), linear order
  __shared__ unsigned sdz[64];      // seeded z (hi word of zkey) per pixel
  int bid = blockIdx.x;
  if (bid >= nC[0]) return;                       // block-uniform exit
  int wkv = work[bid];
  int bin = wkv & (NBIN_ - 1);
  int chunk = wkv >> 10;
  int b = bin >> 8;
  int t = bin & 255;
  int tyT = t >> 4, txT = t & 15;
  int ws = threadIdx.x >> 6, lane = threadIdx.x & 63;
  int pi = tyT * TS_ + (lane >> 3);
  int pj = txT * TS_ + (lane & 7);
  // exact: (2j+1)/128-1 and 1-(2i+1)/128 are multiples of 2^-7 in [-1,1]
  float px = fmaf((float)pj, 0.015625f, -0.9921875f);
  float py = fmaf((float)pi, -0.015625f, 0.9921875f);

  int n = cnt[bin];
  int seg = (chunk << 8) + (ws << 6);
  int base0 = off[bin] + seg;
  int mw = min(n - seg, 64);
  mw = max(mw, 0);

  // coherent z-buffer snapshot, one atomic per pixel per block.
  if (threadIdx.x < 64) {
    unsigned long long s =
        atomicMin(zkey + (size_t)b * NPIX + pi * IMG_ + pj, ~0ull);
    sdz[threadIdx.x] = (unsigned)(s >> 32);
  }

  if (lane < mw) {
    int fid = list[base0 + lane];
    int ia = faces[fid * 3 + 0], ib = faces[fid * 3 + 1],
        ic = faces[fid * 3 + 2];
    const float* vb = vp + (size_t)b * NV_ * 3;
    float X0 = vb[ia * 3 + 0], Y0 = vb[ia * 3 + 1], Z0 = vb[ia * 3 + 2];
    float X1 = vb[ib * 3 + 0], Y1 = vb[ib * 3 + 1], Z1 = vb[ib * 3 + 2];
    float X2 = vb[ic * 3 + 0], Y2 = vb[ic * 3 + 1], Z2 = vb[ic * 3 + 2];
    fd[ws][0][lane] = make_float4(X2 - X1, Y2 - Y1, X1, Y1);   // d21, v1
    fd[ws][1][lane] = make_float4(X0 - X2, Y0 - Y2, X2, Y2);   // d02, v2
    fd[ws][2][lane] = make_float4(X1 - X0, Y1 - Y0, X0, Y0);   // d10, v0
    fd[ws][3][lane] = make_float4(Z0, Z1, Z2, __int_as_float(fid));
    fd[ws][4][lane] =
        make_float4(Z1 * Z2, Z0 * Z2, Z0 * Z1, Z0 * Z1 * Z2);  // approx prods
    zmn[ws][lane] = fminf(Z0, fminf(Z1, Z2));
  }
  __syncthreads();

  // per-lane seed (clamped: NaN/empty -> +inf; all real z positive normals)
  unsigned seed_u = min(sdz[lane], 0x7F800000u);
  float seedf = __uint_as_float(seed_u);
  // wave max of seed (uint order == float order for positives/inf)
  unsigned th1u = seed_u;
  for (int j = 1; j < 64; j <<= 1) {
    unsigned o = (unsigned)__shfl_xor((int)th1u, j, 64);
    th1u = o > th1u ? o : th1u;
  }
  float th1f = __uint_as_float(th1u);

  // ---- pass 1: branchless approx min
  unsigned win_u = 0x7F800000u;
  for (int q = 0; q < mw; ++q) {
    if (zmn[ws][q] > th1f) continue;   // zp >= zmin > seed for all lanes
    float4 A = fd[ws][0][q];
    float4 Bv = fd[ws][1][q];
    float4 Cv = fd[ws][2][q];
    float w0 = A.x * (py - A.w) - A.y * (px - A.z);
    float w1 = Bv.x * (py - Bv.w) - Bv.y * (px - Bv.z);
    float w2 = Cv.x * (py - Cv.w) - Cv.y * (px - Cv.z);
    float area = (w0 + w1) + w2;
    float mn = fminf(w0, fminf(w1, w2));
    bool pred = (area > 0.0f) && !(mn < 0.0f);
    if (!__any(pred)) continue;
    float4 P = fd[ws][4][q];
    float num = (w0 * P.x + w1 * P.y) + w2 * P.z;
    float zpa = (area * P.w) * __builtin_amdgcn_rcpf(num);
    // certainly window-valid (conservative exclusion; NaN fails cmps)
    bool ok = pred && (zpa > 0.1001f) && (zpa < 24.975f);
    unsigned zb = __float_as_uint(zpa);
    if (ok && zb < win_u) win_u = zb;
  }

  // thresholds for pass 2
  unsigned tu = win_u < seed_u ? win_u : seed_u;
  float thrf = __uint_as_float(tu) * 1.001f;       // per-lane; inf stays inf
  unsigned th2u = tu;
  for (int j = 1; j < 64; j <<= 1) {
    unsigned o = (unsigned)__shfl_xor((int)th2u, j, 64);
    th2u = o > th2u ? o : th2u;
  }
  float th2f = __uint_as_float(th2u) * 1.001f;

  // ---- pass 2: collect ambiguous candidates
  unsigned long long qmask = 0ull;
  for (int q = 0; q < mw; ++q) {
    if (zmn[ws][q] > th2f) continue;   // margined: zp >= zmin > min(win,seed)
    float4 A = fd[ws][0][q];
    float4 Bv = fd[ws][1][q];
    float4 Cv = fd[ws][2][q];
    float w0 = A.x * (py - A.w) - A.y * (px - A.z);
    float w1 = Bv.x * (py - Bv.w) - Bv.y * (px - Bv.z);
    float w2 = Cv.x * (py - Cv.w) - Cv.y * (px - Cv.z);
    float area = (w0 + w1) + w2;
    float mn = fminf(w0, fminf(w1, w2));
    bool pred = (area > 0.0f) && !(mn < 0.0f);
    if (!__any(pred)) continue;
    float4 P = fd[ws][4][q];
    float num = (w0 * P.x + w1 * P.y) + w2 * P.z;
    float zpa = (area * P.w) * __builtin_amdgcn_rcpf(num);
    // ambiguous if not provably above thr (NaN-safe) or in window-uncertainty
    bool amb = pred && (!(zpa > thrf) ||
                        (zpa > 0.09989f && zpa < 0.10011f) ||
                        (zpa > 24.9724f && zpa < 25.0276f));
    if (amb) qmask |= 1ull << q;
  }

  // ---- exact chains: per-lane over own candidate set (~2-4 wave iters)
  unsigned long long kb = ~0ull;
  while (__any(qmask != 0ull)) {
    if (qmask != 0ull) {
      int q = __ffsll(qmask) - 1;
      qmask &= qmask - 1;
      float4 A = fd[ws][0][q];
      float4 Bv = fd[ws][1][q];
      float4 Cv = fd[ws][2][q];
      float4 Z = fd[ws][3][q];
      float w0 = A.x * (py - A.w) - A.y * (px - A.z);
      float w1 = Bv.x * (py - Bv.w) - Bv.y * (px - Bv.z);
      float w2 = Cv.x * (py - Cv.w) - Cv.y * (px - Cv.z);
      float area = (w0 + w1) + w2;            // pred held: area > 0
      float b0 = w0 / area, b1 = w1 / area, b2 = w2 / area;
      float invz = (b0 / Z.x + b1 / Z.y) + b2 / Z.z;
      float zp = 1.0f / (invz == 0.0f ? 1.0f : invz);
      if (zp > 0.1f && zp < 25.0f) {
        unsigned long long key =
            ((unsigned long long)__float_as_uint(zp) << 32) |
            (unsigned int)__float_as_int(Z.w);
        if (key < kb) kb = key;
      }
    }
  }

  mg[ws][lane] = kb;
  __syncthreads();
  if (ws == 0) {
    unsigned long long k0 = mg[0][lane];
    unsigned long long k1 = mg[1][lane];
    unsigned long long k2 = mg[2][lane];
    unsigned long long k3 = mg[3][lane];
    k0 = k1 < k0 ? k1 : k0;
    k2 = k3 < k2 ? k3 : k2;
    k0 = k2 < k0 ? k2 : k0;
    if (k0 != ~0ull)
      atomicMin(zkey + (size_t)b * NPIX + pi * IMG_ + pj, k0);
  }
}

// ------------------------------------------------------------------- shading
#define TAP(ty, tx, wexpr)                                                   \
  {                                                                          \
    int ty_ = (ty), tx_ = (tx);                                              \
    float w_ = (wexpr);                                                      \
    float valid_ =                                                           \
        (tx_ >= 0 && tx_ < UV_ && ty_ >= 0 && ty_ < UV_) ? 1.0f : 0.0f;      \
    float wv_ = w_ * valid_;                                                 \
    int cy_ = min(max(ty_, 0), UV_ - 1), cx_ = min(max(tx_, 0), UV_ - 1);    \
    int o_ = cy_ * UV_ + cx_;                                                \
    cr = cr + img[o_] * wv_;                                                 \
    cg = cg + img[UV_ * UV_ + o_] * wv_;                                     \
    cb = cb + img[2 * UV_ * UV_ + o_] * wv_;                                 \
  }

__global__ void __launch_bounds__(256) shade_k(
    const float* __restrict__ vp, const int* __restrict__ faces,
    const float* __restrict__ uv, const float* __restrict__ samp,
    const unsigned long long* __restrict__ zkey, float* __restrict__ out) {
  int idx = blockIdx.x * 256 + threadIdx.x;
  if (idx >= B_ * NPIX) return;
  int b = idx / NPIX;
  int p = idx - b * NPIX;
  int ii = p / IMG_;
  int jj = p - ii * IMG_;

  unsigned long long key = zkey[idx];
  float cr = 0.0f, cg = 0.0f, cb = 0.0f;
  if (key != 0xFFFFFFFFFFFFFFFFull) {
    int f = (int)(key & 0xFFFFFFFFull);
    int ia = faces[f * 3 + 0], ib = faces[f * 3 + 1], ic = faces[f * 3 + 2];
    const float* vb = vp + (size_t)b * NV_ * 3;
    float x0 = vb[ia * 3 + 0], y0 = vb[ia * 3 + 1];
    float x1 = vb[ib * 3 + 0], y1 = vb[ib * 3 + 1];
    float x2 = vb[ic * 3 + 0], y2 = vb[ic * 3 + 1];
    float px = (float)(2 * jj + 1) / 128.0f - 1.0f;
    float py = 1.0f - (float)(2 * ii + 1) / 128.0f;
    float w0 = (x2 - x1) * (py - y1) - (y2 - y1) * (px - x1);
    float w1 = (x0 - x2) * (py - y2) - (y0 - y2) * (px - x2);
    float w2 = (x1 - x0) * (py - y0) - (y1 - y0) * (px - x0);
    float area = (w0 + w1) + w2;
    float s = (area == 0.0f) ? 1.0f : area;
    float b0 = w0 / s, b1 = w1 / s;
    int t0 = min(max((int)floorf(b0 * 3.0f), 0), 2);
    int t1 = min(max((int)floorf(b1 * 3.0f), 0), 2);

    // lazy texture fetch: textures[b,f,t0,t1,*,c] == bilinear(uv_imgs[b],
    // sampler[f, t0*3+t1]); lighting multiplier is exactly 1.0 -> skipped.
    const float* g = samp + ((size_t)f * 9 + (size_t)(t0 * 3 + t1)) * 2;
    float gx = g[0], gy = g[1];
    float x = (gx + 1.0f) * 128.0f - 0.5f;   // (g+1)*(W*0.5)-0.5, W=256
    float y = (gy + 1.0f) * 128.0f - 0.5f;
    float x0f = floorf(x), y0f = floorf(y);
    float wx = x - x0f, wy = y - y0f;
    int xi = (int)x0f, yi = (int)y0f;
    float omwx = 1.0f - wx, omwy = 1.0f - wy;
    const float* img = uv + (size_t)b * 3 * UV_ * UV_;
    // reference accumulation order: (y0,x0)+(y0,x0+1)+(y0+1,x0)+(y0+1,x0+1)
    TAP(yi,     xi,     omwx * omwy)
    TAP(yi,     xi + 1, wx * omwy)
    TAP(yi + 1, xi,     omwx * wy)
    TAP(yi + 1, xi + 1, wx * wy)
  }
  out[((size_t)b * 3 + 0) * NPIX + p] = cr;
  out[((size_t)b * 3 + 1) * NPIX + p] = cg;
  out[((size_t)b * 3 + 2) * NPIX + p] = cb;
}

// ------------------------------------------------------------------- launch
extern "C" void kernel_launch(void* const* d_in, const int* in_sizes, int n_in,
                              void* d_out, int out_size, void* d_ws,
                              size_t ws_size, hipStream_t stream) {
  const float* cam   = (const float*)d_in[0];
  const float* verts = (const float*)d_in[1];
  const float* uv    = (const float*)d_in[2];
  const float* samp  = (const float*)d_in[3];
  const int*   faces = (const int*)d_in[4];

  char* ws = (char*)d_ws;
  size_t o = 0;
  unsigned long long* zkey = (unsigned long long*)(ws + o);
  o += (size_t)B_ * NPIX * 8;                                   // 512 KB
  float* vp = (float*)(ws + o);
  o += ((size_t)B_ * NV_ * 3 * 4 + 1023) & ~1023ull;            // ~331 KB
  int* cnt   = (int*)(ws + o); o += NBIN_ * 4;
  int* offs  = (int*)(ws + o); o += NBIN_ * 4;
  int* cur   = (int*)(ws + o); o += NBIN_ * 4;
  int* nC    = (int*)(ws + o); o += 1024;
  int* work  = (int*)(ws + o); o += (size_t)MAXC_ * 4;          // 36 KB
  int* rects = (int*)(ws + o); o += (size_t)B_ * NF_ * 4;       // 440 KB
  int* list  = (int*)(ws + o);                                  // 8 MB

  hipMemsetAsync(zkey, 0xFF, (size_t)B_ * NPIX * 8, stream);
  hipMemsetAsync(cnt, 0, NBIN_ * 4, stream);
  project_k<<<(B_ * NV_ + 255) / 256, 256, 0, stream>>>(cam, verts, vp);
  dim3 bgrid((NF_ + 255) / 256, B_);
  bin_count_k<<<bgrid, 256, 0, stream>>>(vp, faces, cnt, rects);
  scan_k<<<1, NBIN_, 0, stream>>>(cnt, offs, cur, work, nC);
  bin_fill_k<<<bgrid, 256, 0, stream>>>(rects, cur, list);
  raster_k<<<MAXC_, 256, 0, stream>>>(vp, faces, list, cnt, offs, work, nC,
                                      zkey);
  shade_k<<<(B_ * NPIX + 255) / 256, 256, 0, stream>>>(vp, faces, uv, samp,
                                                       zkey, (float*)d_out);
}